// Round 14
// baseline (52.023 us; speedup 1.0000x reference)
//
#include <hip/hip_runtime.h>

// CARAFE naive upsample: N=2, C=256, H=100, W=100, K=5, G=1, S=2.
// out[n,c,2h+a,2w+b] = sum_{dy,dx} mask[n,dy*5+dx,2h+a,2w+b] * feat[n,c,h+dy-2,w+dx-2]
//
// Journal: R8 = 38.1 us anchor (LDS features RSTR=29, global masks).
// R11: compiler sinks C++-batched loads (VGPR 32, ~2 in flight). R12: masks
// via LDS = 53 us (LDS instr-count wall). R13: sched_barrier pipeline ->
// VGPR 60 (<72 floor for 2 sets + acc) => pin FAILED at C++ level; 37.1 us.
// R14: loads in inline asm + hand-counted vmcnt (the AITER pattern — the
// compiler cannot see or drain them):
//   - mask loads: asm global_load_dwordx2, SADDR=mask base (SGPR pair),
//     32-bit voffset per (dy,dx), offset:800 imm for the a=1 row.
//   - 3-deep pipeline: issue dy 0,1,2 (30 loads); steady state
//     {s_waitcnt vmcnt(20); sched_barrier(0); STAGE FMAs; issue next 10}.
//     In-flight distance ~2 stages (~700 cyc) > L3 latency.
//   - rule #18: sched_barrier(0) after every inline-asm waitcnt.
//   - nontemporal output stores (never re-read; keep L2 for masks).
// VGPR is the instrument: >=112 means the pin held.

typedef float v2f __attribute__((ext_vector_type(2)));

#define N_ 2
#define C_ 256
#define H_ 100
#define W_ 100
#define CC 8
#define HW_ (H_ * W_)
#define OW_ (W_ * 2)
#define OHW_ (HW_ * 4)
#define NCHUNK (C_ / CC)          // 32
#define TW 25
#define TH 10
#define HX 29                     // halo cols (TW+4)
#define NROW 28                   // 14 halo rows x 2 channel-quads
#define RSTR 29                   // float4 row stride: >= HX and odd
#define TILES_X (W_ / TW)         // 4
#define TILES_Y (H_ / TH)         // 10
#define TILES (TILES_X * TILES_Y) // 40

__global__ __launch_bounds__(256) void carafe_kernel(
    const float* __restrict__ feat,
    const float* __restrict__ mask,
    float* __restrict__ out) {

    __shared__ float4 lds4[NROW * RSTR];   // 12,992 B

    const int cchunk = blockIdx.x;
    const int tile   = blockIdx.y;
    const int n      = blockIdx.z;
    const int tx = tile % TILES_X;
    const int ty = tile / TILES_X;
    const int x0 = tx * TW;
    const int y0 = ty * TH;
    const int t = threadIdx.x;
    const int lane = t & 31;
    const int g = t >> 5;

    // ---- stage features (identical to R8) ----
    {
        const float* fb = feat + (n * C_ + cchunk * CC) * HW_;
        const int xx = x0 - 2 + lane;
        const bool xok = (lane < HX) & ((unsigned)xx < (unsigned)W_);
#pragma unroll
        for (int r = 0; r < 4; ++r) {
            const int p = g * 4 + r;
            const int y = p >> 1;
            const int cq = p & 1;
            const int yy = y0 - 2 + y;
            float v0 = 0.f, v1 = 0.f, v2 = 0.f, v3 = 0.f;
            if (xok & ((unsigned)yy < (unsigned)H_) & (p < NROW)) {
                const int o = (cq * 4) * HW_ + yy * W_ + xx;
                v0 = fb[o];
                v1 = fb[o + HW_];
                v2 = fb[o + 2 * HW_];
                v3 = fb[o + 3 * HW_];
            }
            if ((p < NROW) & (lane < HX))
                lds4[p * RSTR + lane] = make_float4(v0, v1, v2, v3);
        }
    }
    __syncthreads();

    if (t >= TH * TW) return;              // 250 compute threads
    const int hl = t / TW;
    const int wl = t % TW;

    v2f a0[CC], a1[CC];
#pragma unroll
    for (int c = 0; c < CC; ++c) { a0[c] = (v2f){0.f, 0.f}; a1[c] = (v2f){0.f, 0.f}; }

    const int oh0 = 2 * (y0 + hl);
    const int ow0 = 2 * (x0 + wl);
    const float* mbase = mask + n * (25 * OHW_);           // block-uniform -> SGPR pair
    const unsigned thr_off = (unsigned)(oh0 * OW_ + ow0) * 4u;  // per-thread byte off

    v2f m0A[5], m1A[5], m0B[5], m1B[5], m0C[5], m1C[5];

// Issue 10 mask loads for row dy into set (M0, M1). offset:800 = OW_*4 (a=1 row).
#define ISSUE(M0, M1, dyv)                                                          \
    do {                                                                            \
        const unsigned vo0 = thr_off + (unsigned)((((dyv) * 5 + 0) * OHW_) * 4);    \
        const unsigned vo1 = thr_off + (unsigned)((((dyv) * 5 + 1) * OHW_) * 4);    \
        const unsigned vo2 = thr_off + (unsigned)((((dyv) * 5 + 2) * OHW_) * 4);    \
        const unsigned vo3 = thr_off + (unsigned)((((dyv) * 5 + 3) * OHW_) * 4);    \
        const unsigned vo4 = thr_off + (unsigned)((((dyv) * 5 + 4) * OHW_) * 4);    \
        asm volatile("global_load_dwordx2 %0, %1, %2 offset:0"   : "=v"(M0[0]) : "v"(vo0), "s"(mbase)); \
        asm volatile("global_load_dwordx2 %0, %1, %2 offset:800" : "=v"(M1[0]) : "v"(vo0), "s"(mbase)); \
        asm volatile("global_load_dwordx2 %0, %1, %2 offset:0"   : "=v"(M0[1]) : "v"(vo1), "s"(mbase)); \
        asm volatile("global_load_dwordx2 %0, %1, %2 offset:800" : "=v"(M1[1]) : "v"(vo1), "s"(mbase)); \
        asm volatile("global_load_dwordx2 %0, %1, %2 offset:0"   : "=v"(M0[2]) : "v"(vo2), "s"(mbase)); \
        asm volatile("global_load_dwordx2 %0, %1, %2 offset:800" : "=v"(M1[2]) : "v"(vo2), "s"(mbase)); \
        asm volatile("global_load_dwordx2 %0, %1, %2 offset:0"   : "=v"(M0[3]) : "v"(vo3), "s"(mbase)); \
        asm volatile("global_load_dwordx2 %0, %1, %2 offset:800" : "=v"(M1[3]) : "v"(vo3), "s"(mbase)); \
        asm volatile("global_load_dwordx2 %0, %1, %2 offset:0"   : "=v"(M0[4]) : "v"(vo4), "s"(mbase)); \
        asm volatile("global_load_dwordx2 %0, %1, %2 offset:800" : "=v"(M1[4]) : "v"(vo4), "s"(mbase)); \
    } while (0)

// Counted wait on our asm loads; sched_barrier stops FMA hoisting (rule #18).
#define WAITV(nv)                                                                   \
    do {                                                                            \
        asm volatile("s_waitcnt vmcnt(" #nv ")");                                   \
        __builtin_amdgcn_sched_barrier(0);                                          \
    } while (0)

#define STAGE(M0, M1, dyv)                                                          \
    do {                                                                            \
        const int ry_ = (hl + (dyv)) * 2;                                           \
        float4 lo_[5], hi_[5];                                                      \
        _Pragma("unroll")                                                           \
        for (int dx = 0; dx < 5; ++dx) {                                            \
            lo_[dx] = lds4[ry_ * RSTR + wl + dx];                                   \
            hi_[dx] = lds4[(ry_ + 1) * RSTR + wl + dx];                             \
        }                                                                           \
        _Pragma("unroll")                                                           \
        for (int dx = 0; dx < 5; ++dx) {                                            \
            const float f_[8] = {lo_[dx].x, lo_[dx].y, lo_[dx].z, lo_[dx].w,        \
                                 hi_[dx].x, hi_[dx].y, hi_[dx].z, hi_[dx].w};       \
            _Pragma("unroll")                                                       \
            for (int c = 0; c < CC; ++c) {                                          \
                const v2f fv_ = {f_[c], f_[c]};                                     \
                a0[c] = __builtin_elementwise_fma(fv_, M0[dx], a0[c]);              \
                a1[c] = __builtin_elementwise_fma(fv_, M1[dx], a1[c]);              \
            }                                                                       \
        }                                                                           \
    } while (0)

    // ---- 3-deep software pipeline with hand-counted vmcnt ----
    ISSUE(m0A, m1A, 0);
    ISSUE(m0B, m1B, 1);
    ISSUE(m0C, m1C, 2);          // 30 outstanding
    WAITV(20);                   // set A landed
    STAGE(m0A, m1A, 0);
    ISSUE(m0A, m1A, 3);          // outstanding: B,C,A3 = 30
    WAITV(20);                   // set B landed
    STAGE(m0B, m1B, 1);
    ISSUE(m0B, m1B, 4);          // outstanding: C,A3,B4 = 30
    WAITV(20);                   // set C landed
    STAGE(m0C, m1C, 2);
    WAITV(10);                   // A3 landed
    STAGE(m0A, m1A, 3);
    WAITV(0);                    // B4 landed
    STAGE(m0B, m1B, 4);

#undef ISSUE
#undef WAITV
#undef STAGE

    float* ob = out + (n * C_ + cchunk * CC) * OHW_ + oh0 * OW_ + ow0;
#pragma unroll
    for (int c = 0; c < CC; ++c) {
        __builtin_nontemporal_store(a0[c], reinterpret_cast<v2f*>(ob + c * OHW_));
        __builtin_nontemporal_store(a1[c], reinterpret_cast<v2f*>(ob + c * OHW_ + OW_));
    }
}

extern "C" void kernel_launch(void* const* d_in, const int* in_sizes, int n_in,
                              void* d_out, int out_size, void* d_ws, size_t ws_size,
                              hipStream_t stream) {
    const float* feat = (const float*)d_in[0];
    const float* mask = (const float*)d_in[1];
    float* out = (float*)d_out;

    dim3 grid(NCHUNK, TILES, N_);   // 32 x 40 x 2 = 2560 blocks
    carafe_kernel<<<grid, 256, 0, stream>>>(feat, mask, out);
}

// Round 15
// 39.641 us; speedup vs baseline: 1.3123x; 1.3123x over previous
//
#include <hip/hip_runtime.h>

// CARAFE naive upsample: N=2, C=256, H=100, W=100, K=5, G=1, S=2.
// out[n,c,2h+a,2w+b] = sum_{dy,dx} mask[n,dy*5+dx,2h+a,2w+b] * feat[n,c,h+dy-2,w+dx-2]
//
// Journal: R8 = 38.1 us anchor. R11: occupancy 56% -> dur flat (occupancy
// not the lever). R12: masks via LDS = 53 us (LDS instr wall). R13/R14:
// sched_barrier / inline-asm vmcnt pipelines -> flat/regression (mask
// LATENCY not the binding term; R14 nt-stores also amplified WRITE 80->105MB).
// Common residual: per-thread VMEM instr count (82 small ops, 8B each).
// R15: split the output quad across threads -> thread owns ONE output row
//   (fixed a) x 4 output cols (2 low-res pixels):
//   - mask read per tap = ONE lane-dense dwordx4 (25 total, was 50x8B)
//   - stores = 8x f4 (was 16x8B)            => VMEM instrs 82 -> 49
//   - ds_reads 50 -> 60 b128 (6-wide window serves both pixels)
//   - VALU unchanged (400 pk-fma)
//   Tile 20x12, CC=8, 240/256 compute threads, 2880 blocks x 4 waves
//   (MORE waves than R8 - avoids the R6/R9 wave-count trap). No sched
//   pinning, normal stores.

typedef float v4f __attribute__((ext_vector_type(4)));

#define N_ 2
#define C_ 256
#define H_ 100
#define W_ 100
#define CC 8
#define HW_ (H_ * W_)
#define OW_ (W_ * 2)
#define OHW_ (HW_ * 4)
#define NCHUNK (C_ / CC)          // 32
#define TW 20                     // tile x extent (10 pixel-pairs)
#define TH 12                     // tile y extent
#define NP 10                     // pairs per row
#define HX 24                     // halo cols = TW+4
#define NROW 32                   // (TH+4) halo rows x 2 channel-quads
#define RSTR 25                   // f4 row stride (odd, >= HX)
#define TILES_X (W_ / TW)         // 5
#define TILES_Y ((H_ + TH - 1) / TH)  // 9 (covers 108 rows, tail masked)

__global__ __launch_bounds__(256) void carafe_kernel(
    const float* __restrict__ feat,
    const float* __restrict__ mask,
    float* __restrict__ out) {

    // row p = y*2 + cq (y: halo row 0..15, cq: channel quad); f4 index
    // p*RSTR + x, innermost c%4.
    __shared__ float4 lds4[NROW * RSTR];   // 32*25*16 = 12,800 B

    const int cchunk = blockIdx.x;         // chunk-major: mask L2 sharing
    const int tile   = blockIdx.y;
    const int n      = blockIdx.z;
    const int tx = tile % TILES_X;
    const int ty = tile / TILES_X;
    const int x0 = tx * TW;
    const int y0 = ty * TH;
    const int t = threadIdx.x;
    const int lane = t & 31;
    const int g = t >> 5;                  // 8 groups

    // ---- stage features (R8 pattern, exactly 32 rows) ----
    {
        const float* fb = feat + (n * C_ + cchunk * CC) * HW_;
        const int xx = x0 - 2 + lane;
        const bool xok = (lane < HX) & ((unsigned)xx < (unsigned)W_);
#pragma unroll
        for (int r = 0; r < 4; ++r) {
            const int p = g * 4 + r;       // 0..31 == NROW-1
            const int y = p >> 1;
            const int cq = p & 1;
            const int yy = y0 - 2 + y;
            float v0 = 0.f, v1 = 0.f, v2 = 0.f, v3 = 0.f;
            if (xok & ((unsigned)yy < (unsigned)H_)) {
                const int o = (cq * 4) * HW_ + yy * W_ + xx;
                v0 = fb[o];
                v1 = fb[o + HW_];
                v2 = fb[o + 2 * HW_];
                v3 = fb[o + 3 * HW_];
            }
            if (lane < HX)
                lds4[p * RSTR + lane] = make_float4(v0, v1, v2, v3);
        }
    }
    __syncthreads();

    // ---- compute: thread = (hl, a, wp): one output row x 4 cols x 8 ch ----
    if (t >= TH * 2 * NP) return;          // 240 compute threads
    const int hl  = t / (2 * NP);          // 0..11
    const int rem = t % (2 * NP);
    const int a   = rem / NP;              // output sub-row 0/1
    const int wp  = rem % NP;              // pixel pair 0..9

    const int h = y0 + hl;
    if (h >= H_) return;                   // tail tile rows (no barrier after)

    const int oh  = 2 * h + a;
    const int ow0 = 2 * x0 + 4 * wp;       // f4-aligned
    const float* mbase = mask + n * (25 * OHW_) + oh * OW_ + ow0;

    v4f acc[CC];                           // [c] = output cols ow0..ow0+3
#pragma unroll
    for (int c = 0; c < CC; ++c) acc[c] = (v4f){0.f, 0.f, 0.f, 0.f};

#pragma unroll 1
    for (int dy = 0; dy < 5; ++dy) {
        const int p0 = ((hl + dy) * 2) * RSTR + 2 * wp;   // quad 0 row base
        const int p1 = p0 + RSTR;                          // quad 1

        // one lane-dense f4 mask load per tap
        v4f m[5];
#pragma unroll
        for (int dx = 0; dx < 5; ++dx)
            m[dx] = *reinterpret_cast<const v4f*>(mbase + ((dy * 5 + dx)) * OHW_);

        // 12 b128 feature reads serve both pixels' 5-tap windows
        float4 f0[6], f1[6];
#pragma unroll
        for (int j = 0; j < 6; ++j) {
            f0[j] = lds4[p0 + j];          // c0..3 at window col j
            f1[j] = lds4[p1 + j];          // c4..7
        }

#pragma unroll
        for (int dx = 0; dx < 5; ++dx) {
#pragma unroll
            for (int c = 0; c < CC; ++c) {
                const float fl = (c < 4) ? f0[dx][c]     : f1[dx][c - 4];     // pixel 0
                const float fr = (c < 4) ? f0[dx + 1][c] : f1[dx + 1][c - 4]; // pixel 1
                const v4f fv = {fl, fl, fr, fr};
                acc[c] = __builtin_elementwise_fma(fv, m[dx], acc[c]);  // 2x v_pk_fma
            }
        }
    }

    float* ob = out + (n * C_ + cchunk * CC) * OHW_ + oh * OW_ + ow0;
#pragma unroll
    for (int c = 0; c < CC; ++c)
        *reinterpret_cast<v4f*>(ob + c * OHW_) = acc[c];
}

extern "C" void kernel_launch(void* const* d_in, const int* in_sizes, int n_in,
                              void* d_out, int out_size, void* d_ws, size_t ws_size,
                              hipStream_t stream) {
    const float* feat = (const float*)d_in[0];
    const float* mask = (const float*)d_in[1];
    float* out = (float*)d_out;

    dim3 grid(NCHUNK, TILES_X * TILES_Y, N_);   // 32 x 45 x 2 = 2880 blocks
    carafe_kernel<<<grid, 256, 0, stream>>>(feat, mask, out);
}